// Round 1
// baseline (280.636 us; speedup 1.0000x reference)
//
#include <hip/hip_runtime.h>

typedef _Float16 f16;
typedef f16 f16x8 __attribute__((ext_vector_type(8)));
typedef float f32x4 __attribute__((ext_vector_type(4)));

#define N_EMBD 768
#define HS 64
#define NB 4
#define SEQ 4096
#define NTOK (NB * SEQ)
#define KSTEPS (N_EMBD / 32)   // 24

// ws layout (bytes)
#define OFF_Q  (3 * KSTEPS * 4 * 64 * 16)        // packed weights: 294912
#define OFF_K  (OFF_Q + NTOK * HS * 2)           // q fp16: 2 MB
#define OFF_VT (OFF_K + NTOK * HS * 2)           // k fp16: 2 MB; vT fp16: 2 MB

// ---------------------------------------------------------------------------
// Pack Wq/Wk/Wv (fp32 [768][64]) into MFMA B-fragment order, fp16.
// Fragment layout for mfma_f32_16x16x32: B[k=quad*8+j][n=lane&15].
// packed index = ((mu*KSTEPS + kstep)*4 + ct)*64 + lane, 8 f16 each.
// Scale 1/8 (= H^-0.5) folded into Wq (exact in fp16: power of two).
// ---------------------------------------------------------------------------
__global__ __launch_bounds__(256) void pack_w(const float* __restrict__ Wk,
                                              const float* __restrict__ Wq,
                                              const float* __restrict__ Wv,
                                              f16* __restrict__ wpk) {
  int tid = blockIdx.x * 256 + threadIdx.x;      // 72*256 = 18432 exactly
  int mu = tid / (KSTEPS * 256);
  int rem = tid % (KSTEPS * 256);
  int kstep = rem >> 8;
  int ct = (rem >> 6) & 3;
  int lane = rem & 63;
  int col = ct * 16 + (lane & 15);
  int k0 = kstep * 32 + (lane >> 4) * 8;
  const float* src = (mu == 0) ? Wq : ((mu == 1) ? Wk : Wv);
  float scale = (mu == 0) ? 0.125f : 1.0f;
  f16x8 v;
#pragma unroll
  for (int j = 0; j < 8; j++) v[j] = (f16)(src[(k0 + j) * HS + col] * scale);
  *((f16x8*)wpk + tid) = v;
}

// ---------------------------------------------------------------------------
// QKV projection: C[m][n] = sum_k x[m][k] * W[k][n], M=16384, K=768, N=3*64.
// One block = 64 rows (4 waves x 16 rows). Each wave does 12 col-tiles so x
// is read exactly once (48 MB). q,k stored [tok][64] fp16; v stored
// transposed per batch: vT[b][dim][t] so attention B-fragments are contiguous.
// ---------------------------------------------------------------------------
__global__ __launch_bounds__(256) void proj(const float* __restrict__ x,
                                            const f16x8* __restrict__ wpk,
                                            f16* __restrict__ qb,
                                            f16* __restrict__ kb,
                                            f16* __restrict__ vtb) {
  int w = threadIdx.x >> 6, lane = threadIdx.x & 63;
  int l15 = lane & 15, quad = lane >> 4;
  int r0 = blockIdx.x * 64 + w * 16;
  int arow = r0 + l15;
  const float* xp = x + (size_t)arow * N_EMBD + quad * 8;

  f32x4 acc[12];
#pragma unroll
  for (int i = 0; i < 12; i++) acc[i] = (f32x4)0.0f;

  for (int ks = 0; ks < KSTEPS; ks++) {
    f32x4 a0 = *(const f32x4*)(xp + ks * 32);
    f32x4 a1 = *(const f32x4*)(xp + ks * 32 + 4);
    f16x8 af;
#pragma unroll
    for (int j = 0; j < 4; j++) { af[j] = (f16)a0[j]; af[4 + j] = (f16)a1[j]; }
#pragma unroll
    for (int mu = 0; mu < 3; mu++) {
#pragma unroll
      for (int ct = 0; ct < 4; ct++) {
        f16x8 bfr = wpk[((mu * KSTEPS + ks) * 4 + ct) * 64 + lane];
        acc[mu * 4 + ct] =
            __builtin_amdgcn_mfma_f32_16x16x32_f16(af, bfr, acc[mu * 4 + ct], 0, 0, 0);
      }
    }
  }
  // C/D layout: col = lane&15, row = quad*4 + reg  [verified m89/m91]
#pragma unroll
  for (int ct = 0; ct < 4; ct++) {
#pragma unroll
    for (int reg = 0; reg < 4; reg++) {
      int row = r0 + quad * 4 + reg;
      int col = ct * 16 + l15;
      qb[row * HS + col] = (f16)acc[0 * 4 + ct][reg];
      kb[row * HS + col] = (f16)acc[1 * 4 + ct][reg];
      int bb = row >> 12, t = row & (SEQ - 1);
      vtb[((bb * HS + col) << 12) + t] = (f16)acc[2 * 4 + ct][reg];
    }
  }
}

// ---------------------------------------------------------------------------
// Flash attention, causal. Block = 64 Q-rows (4 waves x 16 rows), loop over
// 64-key blocks up to the diagonal. P transposed C-layout -> A-layout via a
// wave-private padded LDS tile (stride 72: quad pairs 2-way alias only).
// ---------------------------------------------------------------------------
__global__ __launch_bounds__(256) void attn(const f16* __restrict__ qb,
                                            const f16* __restrict__ kb,
                                            const f16* __restrict__ vtb,
                                            float* __restrict__ out) {
  __shared__ __align__(16) f16 pbuf[4][16][72];
  int w = threadIdx.x >> 6, lane = threadIdx.x & 63;
  int l15 = lane & 15, quad = lane >> 4;
  int qt = blockIdx.x, b = blockIdx.y;
  int qr0 = qt * 64 + w * 16;          // within-batch row base for this wave
  int gq = b * SEQ + qr0;              // global token base

  f16x8 qa[2];
  {
    const f16* qrow = qb + (size_t)(gq + l15) * HS + quad * 8;
    qa[0] = *(const f16x8*)(qrow);
    qa[1] = *(const f16x8*)(qrow + 32);
  }

  f32x4 o[4];
#pragma unroll
  for (int i = 0; i < 4; i++) o[i] = (f32x4)0.0f;
  float m[4], l[4];
#pragma unroll
  for (int r = 0; r < 4; r++) { m[r] = -INFINITY; l[r] = 0.0f; }

  const f16* kb_b = kb + (size_t)b * SEQ * HS;
  const f16* vt_b = vtb + (size_t)b * HS * SEQ;

  for (int kbk = 0; kbk <= qt; kbk++) {
    int key0 = kbk * 64;
    // S = Q K^T  (scale folded into q)
    f32x4 s[4];
#pragma unroll
    for (int kt = 0; kt < 4; kt++) s[kt] = (f32x4)0.0f;
#pragma unroll
    for (int ks = 0; ks < 2; ks++) {
#pragma unroll
      for (int kt = 0; kt < 4; kt++) {
        const f16* kp = kb_b + (size_t)(key0 + kt * 16 + l15) * HS + ks * 32 + quad * 8;
        f16x8 bfr = *(const f16x8*)kp;
        s[kt] = __builtin_amdgcn_mfma_f32_16x16x32_f16(qa[ks], bfr, s[kt], 0, 0, 0);
      }
    }
    // causal mask: only the diagonal block needs it
    if (kbk == qt) {
#pragma unroll
      for (int kt = 0; kt < 4; kt++) {
        int key = key0 + kt * 16 + l15;
#pragma unroll
        for (int r = 0; r < 4; r++) {
          int qrow = qr0 + quad * 4 + r;
          if (key > qrow) s[kt][r] = -INFINITY;
        }
      }
    }
    // online softmax; row r of this wave's 16 lives at lanes (quad fixed), reg r
    float p[4][4], alpha[4];
#pragma unroll
    for (int r = 0; r < 4; r++) {
      float mx = fmaxf(fmaxf(s[0][r], s[1][r]), fmaxf(s[2][r], s[3][r]));
#pragma unroll
      for (int off = 1; off < 16; off <<= 1) mx = fmaxf(mx, __shfl_xor(mx, off, 64));
      float mn = fmaxf(m[r], mx);
      alpha[r] = __expf(m[r] - mn);
      m[r] = mn;
      float sum = 0.0f;
#pragma unroll
      for (int kt = 0; kt < 4; kt++) {
        float e = __expf(s[kt][r] - mn);
        p[kt][r] = e;
        sum += e;
      }
#pragma unroll
      for (int off = 1; off < 16; off <<= 1) sum += __shfl_xor(sum, off, 64);
      l[r] = l[r] * alpha[r] + sum;
    }
#pragma unroll
    for (int dt = 0; dt < 4; dt++)
#pragma unroll
      for (int r = 0; r < 4; r++) o[dt][r] *= alpha[r];

    // P: C-layout -> LDS [row][key] (A-layout source). Wave-private; DS ops
    // from one wave execute in order, no barrier needed.
#pragma unroll
    for (int kt = 0; kt < 4; kt++)
#pragma unroll
      for (int r = 0; r < 4; r++)
        pbuf[w][quad * 4 + r][kt * 16 + l15] = (f16)p[kt][r];

    // O += P V
#pragma unroll
    for (int ks = 0; ks < 2; ks++) {
      f16x8 pa = *(const f16x8*)&pbuf[w][l15][ks * 32 + quad * 8];
#pragma unroll
      for (int dt = 0; dt < 4; dt++) {
        const f16* vp = vt_b + (size_t)(dt * 16 + l15) * SEQ + key0 + ks * 32 + quad * 8;
        f16x8 vfr = *(const f16x8*)vp;
        o[dt] = __builtin_amdgcn_mfma_f32_16x16x32_f16(pa, vfr, o[dt], 0, 0, 0);
      }
    }
  }
  // epilogue: divide by l, store fp32
#pragma unroll
  for (int dt = 0; dt < 4; dt++) {
#pragma unroll
    for (int r = 0; r < 4; r++) {
      int qrow = qr0 + quad * 4 + r;
      out[(size_t)(b * SEQ + qrow) * HS + dt * 16 + l15] = o[dt][r] / l[r];
    }
  }
}

extern "C" void kernel_launch(void* const* d_in, const int* in_sizes, int n_in,
                              void* d_out, int out_size, void* d_ws, size_t ws_size,
                              hipStream_t stream) {
  const float* x  = (const float*)d_in[0];
  const float* Wk = (const float*)d_in[1];
  const float* Wq = (const float*)d_in[2];
  const float* Wv = (const float*)d_in[3];
  float* out = (float*)d_out;

  f16* wpk = (f16*)d_ws;
  f16* qb  = (f16*)((char*)d_ws + OFF_Q);
  f16* kbf = (f16*)((char*)d_ws + OFF_K);
  f16* vtb = (f16*)((char*)d_ws + OFF_VT);

  pack_w<<<dim3(72), dim3(256), 0, stream>>>(Wk, Wq, Wv, wpk);
  proj<<<dim3(NTOK / 64), dim3(256), 0, stream>>>(x, (const f16x8*)wpk, qb, kbf, vtb);
  attn<<<dim3(SEQ / 64, NB), dim3(256), 0, stream>>>(qb, kbf, vtb, out);
}

// Round 2
// 197.691 us; speedup vs baseline: 1.4196x; 1.4196x over previous
//
#include <hip/hip_runtime.h>

typedef _Float16 f16;
typedef f16 f16x8 __attribute__((ext_vector_type(8)));
typedef float f32x4 __attribute__((ext_vector_type(4)));

#define N_EMBD 768
#define HS 64
#define NB 4
#define SEQ 4096
#define NTOK (NB * SEQ)
#define KSTEPS (N_EMBD / 32)   // 24

// ws layout (bytes)
#define OFF_Q  (3 * KSTEPS * 4 * 64 * 16)        // packed weights: 294912
#define OFF_K  (OFF_Q + NTOK * HS * 2)
#define OFF_VT (OFF_K + NTOK * HS * 2)
#define OFF_OP (OFF_VT + NTOK * HS * 2)          // partial O fp16: 256*8*4096*2
#define OFF_ML (OFF_OP + 256 * 8 * 4096 * 2)     // m,l fp32: 256*8*128*4
#define WS_NEED (OFF_ML + 256 * 8 * 128 * 4)     // ~24.4 MB

// ---------------------------------------------------------------------------
// Pack Wq/Wk/Wv (fp32 [768][64]) into MFMA B-fragment order, fp16.
// B[k=quad*8+j][n=lane&15]; packed idx = ((mu*KSTEPS+ks)*4+ct)*64+lane.
// Scale 1/8 folded into Wq (exact).
// ---------------------------------------------------------------------------
__global__ __launch_bounds__(256) void pack_w(const float* __restrict__ Wk,
                                              const float* __restrict__ Wq,
                                              const float* __restrict__ Wv,
                                              f16* __restrict__ wpk) {
  int tid = blockIdx.x * 256 + threadIdx.x;      // 72*256 = 18432 exactly
  int mu = tid / (KSTEPS * 256);
  int rem = tid % (KSTEPS * 256);
  int kstep = rem >> 8;
  int ct = (rem >> 6) & 3;
  int lane = rem & 63;
  int col = ct * 16 + (lane & 15);
  int k0 = kstep * 32 + (lane >> 4) * 8;
  const float* src = (mu == 0) ? Wq : ((mu == 1) ? Wk : Wv);
  float scale = (mu == 0) ? 0.125f : 1.0f;
  f16x8 v;
#pragma unroll
  for (int j = 0; j < 8; j++) v[j] = (f16)(src[(k0 + j) * HS + col] * scale);
  *((f16x8*)wpk + tid) = v;
}

// ---------------------------------------------------------------------------
// QKV projection, K-split x4: block = 4 waves sharing 16 rows; wave w takes
// ksteps [w*6, w*6+6). LDS reduction, wave 0 does epilogue. Grid = NTOK/16 =
// 1024 blocks -> 16 waves/CU (vs 4 before). x read exactly once (48 MB).
// ---------------------------------------------------------------------------
__global__ __launch_bounds__(256) void proj(const float* __restrict__ x,
                                            const f16x8* __restrict__ wpk,
                                            f16* __restrict__ qb,
                                            f16* __restrict__ kb,
                                            f16* __restrict__ vtb) {
  __shared__ f32x4 red[3][12][64];               // 36 KB
  int w = threadIdx.x >> 6, lane = threadIdx.x & 63;
  int l15 = lane & 15, quad = lane >> 4;
  int r0 = blockIdx.x * 16;
  int arow = r0 + l15;
  const float* xp = x + (size_t)arow * N_EMBD + quad * 8;

  f32x4 acc[12];
#pragma unroll
  for (int i = 0; i < 12; i++) acc[i] = (f32x4)0.0f;

  int ks0 = w * 6;
#pragma unroll
  for (int kk = 0; kk < 6; kk++) {
    int ks = ks0 + kk;
    f32x4 a0 = *(const f32x4*)(xp + ks * 32);
    f32x4 a1 = *(const f32x4*)(xp + ks * 32 + 4);
    f16x8 af;
#pragma unroll
    for (int j = 0; j < 4; j++) { af[j] = (f16)a0[j]; af[4 + j] = (f16)a1[j]; }
#pragma unroll
    for (int mu = 0; mu < 3; mu++) {
#pragma unroll
      for (int ct = 0; ct < 4; ct++) {
        f16x8 bfr = wpk[((mu * KSTEPS + ks) * 4 + ct) * 64 + lane];
        acc[mu * 4 + ct] =
            __builtin_amdgcn_mfma_f32_16x16x32_f16(af, bfr, acc[mu * 4 + ct], 0, 0, 0);
      }
    }
  }
  if (w) {
#pragma unroll
    for (int i = 0; i < 12; i++) red[w - 1][i][lane] = acc[i];
  }
  __syncthreads();
  if (w == 0) {
#pragma unroll
    for (int i = 0; i < 12; i++) {
      acc[i] += red[0][i][lane];
      acc[i] += red[1][i][lane];
      acc[i] += red[2][i][lane];
    }
    // C/D layout: col = lane&15, row = quad*4 + reg
#pragma unroll
    for (int ct = 0; ct < 4; ct++) {
#pragma unroll
      for (int reg = 0; reg < 4; reg++) {
        int row = r0 + quad * 4 + reg;
        int col = ct * 16 + l15;
        qb[row * HS + col] = (f16)acc[0 * 4 + ct][reg];
        kb[row * HS + col] = (f16)acc[1 * 4 + ct][reg];
        int bb = row >> 12, t = row & (SEQ - 1);
        vtb[((bb * HS + col) << 12) + t] = (f16)acc[2 * 4 + ct][reg];
      }
    }
  }
}

// ---------------------------------------------------------------------------
// Flash attention partial pass, split-K over key segments of <=8 key-blocks.
// blockIdx.x = p in [0,288) encodes (qt, seg) via triangular enumeration;
// blockIdx.y = batch. 1152 blocks total, max 8 iterations each (balanced).
// Writes unnormalized O (fp16) + m,l (fp32) per (qtile,seg) to ws.
// ---------------------------------------------------------------------------
__global__ __launch_bounds__(256) void attn_part(const f16* __restrict__ qb,
                                                 const f16* __restrict__ kb,
                                                 const f16* __restrict__ vtb,
                                                 f16* __restrict__ opart,
                                                 float* __restrict__ ml) {
  __shared__ __align__(16) f16 pbuf[4][16][72];
  int w = threadIdx.x >> 6, lane = threadIdx.x & 63;
  int l15 = lane & 15, quad = lane >> 4;
  int p = blockIdx.x, b = blockIdx.y;
  int g = 0;
  while (p >= 4 * (g + 1) * (g + 2)) g++;        // group g: qt in [8g, 8g+8)
  int rem = p - 4 * g * (g + 1);
  int j = rem / (g + 1);
  int s = rem - j * (g + 1);
  int qt = 8 * g + j;
  int kb_beg = s * 8;
  int kb_end = (s * 8 + 8 < qt + 1) ? (s * 8 + 8) : (qt + 1);

  int qr0 = qt * 64 + w * 16;
  int gq = b * SEQ + qr0;

  f16x8 qa[2];
  {
    const f16* qrow = qb + (size_t)(gq + l15) * HS + quad * 8;
    qa[0] = *(const f16x8*)(qrow);
    qa[1] = *(const f16x8*)(qrow + 32);
  }

  f32x4 o[4];
#pragma unroll
  for (int i = 0; i < 4; i++) o[i] = (f32x4)0.0f;
  float m[4], l[4];
#pragma unroll
  for (int r = 0; r < 4; r++) { m[r] = -INFINITY; l[r] = 0.0f; }

  const f16* kb_b = kb + (size_t)b * SEQ * HS;
  const f16* vt_b = vtb + (size_t)b * HS * SEQ;

  for (int kbk = kb_beg; kbk < kb_end; kbk++) {
    int key0 = kbk * 64;
    f32x4 sc[4];
#pragma unroll
    for (int kt = 0; kt < 4; kt++) sc[kt] = (f32x4)0.0f;
#pragma unroll
    for (int ks = 0; ks < 2; ks++) {
#pragma unroll
      for (int kt = 0; kt < 4; kt++) {
        const f16* kp = kb_b + (size_t)(key0 + kt * 16 + l15) * HS + ks * 32 + quad * 8;
        f16x8 bfr = *(const f16x8*)kp;
        sc[kt] = __builtin_amdgcn_mfma_f32_16x16x32_f16(qa[ks], bfr, sc[kt], 0, 0, 0);
      }
    }
    if (kbk == qt) {                              // diagonal block: causal mask
#pragma unroll
      for (int kt = 0; kt < 4; kt++) {
        int key = key0 + kt * 16 + l15;
#pragma unroll
        for (int r = 0; r < 4; r++) {
          int qrow = qr0 + quad * 4 + r;
          if (key > qrow) sc[kt][r] = -INFINITY;
        }
      }
    }
    float pv[4][4], alpha[4];
#pragma unroll
    for (int r = 0; r < 4; r++) {
      float mx = fmaxf(fmaxf(sc[0][r], sc[1][r]), fmaxf(sc[2][r], sc[3][r]));
#pragma unroll
      for (int off = 1; off < 16; off <<= 1) mx = fmaxf(mx, __shfl_xor(mx, off, 64));
      float mn = fmaxf(m[r], mx);
      alpha[r] = __expf(m[r] - mn);
      m[r] = mn;
      float sum = 0.0f;
#pragma unroll
      for (int kt = 0; kt < 4; kt++) {
        float e = __expf(sc[kt][r] - mn);
        pv[kt][r] = e;
        sum += e;
      }
#pragma unroll
      for (int off = 1; off < 16; off <<= 1) sum += __shfl_xor(sum, off, 64);
      l[r] = l[r] * alpha[r] + sum;
    }
#pragma unroll
    for (int dt = 0; dt < 4; dt++)
#pragma unroll
      for (int r = 0; r < 4; r++) o[dt][r] *= alpha[r];

    // transpose P: C-layout -> A-layout via wave-private LDS (no barrier)
#pragma unroll
    for (int kt = 0; kt < 4; kt++)
#pragma unroll
      for (int r = 0; r < 4; r++)
        pbuf[w][quad * 4 + r][kt * 16 + l15] = (f16)pv[kt][r];

#pragma unroll
    for (int ks = 0; ks < 2; ks++) {
      f16x8 pa = *(const f16x8*)&pbuf[w][l15][ks * 32 + quad * 8];
#pragma unroll
      for (int dt = 0; dt < 4; dt++) {
        const f16* vp = vt_b + (size_t)(dt * 16 + l15) * SEQ + key0 + ks * 32 + quad * 8;
        f16x8 vfr = *(const f16x8*)vp;
        o[dt] = __builtin_amdgcn_mfma_f32_16x16x32_f16(pa, vfr, o[dt], 0, 0, 0);
      }
    }
  }
  // store partials
  int slot = (b * 64 + qt) * 8 + s;
  f16* op = opart + (size_t)slot * 4096;
#pragma unroll
  for (int dt = 0; dt < 4; dt++)
#pragma unroll
    for (int r = 0; r < 4; r++)
      op[(w * 16 + quad * 4 + r) * 64 + dt * 16 + l15] = (f16)o[dt][r];
  if (l15 == 0) {
#pragma unroll
    for (int r = 0; r < 4; r++) {
      int lr = w * 16 + quad * 4 + r;
      ml[slot * 128 + lr] = m[r];
      ml[slot * 128 + 64 + lr] = l[r];
    }
  }
}

// ---------------------------------------------------------------------------
// Combine: merge per-segment partials. 256 blocks (one per q-tile), thread =
// (row, 16-dim chunk). Recompute exp weights in pass 2 (no dynamic array).
// ---------------------------------------------------------------------------
__global__ __launch_bounds__(256) void attn_combine(const f16* __restrict__ opart,
                                                    const float* __restrict__ ml,
                                                    float* __restrict__ out) {
  int blk = blockIdx.x;
  int b = blk >> 6, qt = blk & 63;
  int nseg = (qt >> 3) + 1;
  int tid = threadIdx.x;
  int r = tid >> 2, d0 = (tid & 3) * 16;
  int base_slot = (b * 64 + qt) * 8;

  float M = -INFINITY;
  for (int s = 0; s < nseg; s++) M = fmaxf(M, ml[(base_slot + s) * 128 + r]);
  float L = 0.0f;
  for (int s = 0; s < nseg; s++) {
    float e = __expf(ml[(base_slot + s) * 128 + r] - M);
    L += ml[(base_slot + s) * 128 + 64 + r] * e;
  }
  float acc[16];
#pragma unroll
  for (int i = 0; i < 16; i++) acc[i] = 0.0f;
  for (int s = 0; s < nseg; s++) {
    float e = __expf(ml[(base_slot + s) * 128 + r] - M);
    const f16x8* op = (const f16x8*)(opart + (size_t)(base_slot + s) * 4096 + r * 64 + d0);
    f16x8 a = op[0], c = op[1];
#pragma unroll
    for (int i = 0; i < 8; i++) {
      acc[i] += e * (float)a[i];
      acc[8 + i] += e * (float)c[i];
    }
  }
  float inv = 1.0f / L;
  float* po = out + ((size_t)(b * SEQ + qt * 64 + r)) * HS + d0;
#pragma unroll
  for (int i = 0; i < 16; i++) po[i] = acc[i] * inv;
}

// ---------------------------------------------------------------------------
// Fallback monolithic attention (used only if ws_size < WS_NEED).
// ---------------------------------------------------------------------------
__global__ __launch_bounds__(256) void attn_mono(const f16* __restrict__ qb,
                                                 const f16* __restrict__ kb,
                                                 const f16* __restrict__ vtb,
                                                 float* __restrict__ out) {
  __shared__ __align__(16) f16 pbuf[4][16][72];
  int w = threadIdx.x >> 6, lane = threadIdx.x & 63;
  int l15 = lane & 15, quad = lane >> 4;
  int qt = blockIdx.x, b = blockIdx.y;
  int qr0 = qt * 64 + w * 16;
  int gq = b * SEQ + qr0;
  f16x8 qa[2];
  {
    const f16* qrow = qb + (size_t)(gq + l15) * HS + quad * 8;
    qa[0] = *(const f16x8*)(qrow);
    qa[1] = *(const f16x8*)(qrow + 32);
  }
  f32x4 o[4];
#pragma unroll
  for (int i = 0; i < 4; i++) o[i] = (f32x4)0.0f;
  float m[4], l[4];
#pragma unroll
  for (int r = 0; r < 4; r++) { m[r] = -INFINITY; l[r] = 0.0f; }
  const f16* kb_b = kb + (size_t)b * SEQ * HS;
  const f16* vt_b = vtb + (size_t)b * HS * SEQ;
  for (int kbk = 0; kbk <= qt; kbk++) {
    int key0 = kbk * 64;
    f32x4 sc[4];
#pragma unroll
    for (int kt = 0; kt < 4; kt++) sc[kt] = (f32x4)0.0f;
#pragma unroll
    for (int ks = 0; ks < 2; ks++)
#pragma unroll
      for (int kt = 0; kt < 4; kt++) {
        const f16* kp = kb_b + (size_t)(key0 + kt * 16 + l15) * HS + ks * 32 + quad * 8;
        sc[kt] = __builtin_amdgcn_mfma_f32_16x16x32_f16(qa[ks], *(const f16x8*)kp, sc[kt], 0, 0, 0);
      }
    if (kbk == qt) {
#pragma unroll
      for (int kt = 0; kt < 4; kt++) {
        int key = key0 + kt * 16 + l15;
#pragma unroll
        for (int r = 0; r < 4; r++)
          if (key > qr0 + quad * 4 + r) sc[kt][r] = -INFINITY;
      }
    }
    float pv[4][4], alpha[4];
#pragma unroll
    for (int r = 0; r < 4; r++) {
      float mx = fmaxf(fmaxf(sc[0][r], sc[1][r]), fmaxf(sc[2][r], sc[3][r]));
#pragma unroll
      for (int off = 1; off < 16; off <<= 1) mx = fmaxf(mx, __shfl_xor(mx, off, 64));
      float mn = fmaxf(m[r], mx);
      alpha[r] = __expf(m[r] - mn);
      m[r] = mn;
      float sum = 0.0f;
#pragma unroll
      for (int kt = 0; kt < 4; kt++) { float e = __expf(sc[kt][r] - mn); pv[kt][r] = e; sum += e; }
#pragma unroll
      for (int off = 1; off < 16; off <<= 1) sum += __shfl_xor(sum, off, 64);
      l[r] = l[r] * alpha[r] + sum;
    }
#pragma unroll
    for (int dt = 0; dt < 4; dt++)
#pragma unroll
      for (int r = 0; r < 4; r++) o[dt][r] *= alpha[r];
#pragma unroll
    for (int kt = 0; kt < 4; kt++)
#pragma unroll
      for (int r = 0; r < 4; r++)
        pbuf[w][quad * 4 + r][kt * 16 + l15] = (f16)pv[kt][r];
#pragma unroll
    for (int ks = 0; ks < 2; ks++) {
      f16x8 pa = *(const f16x8*)&pbuf[w][l15][ks * 32 + quad * 8];
#pragma unroll
      for (int dt = 0; dt < 4; dt++) {
        const f16* vp = vt_b + (size_t)(dt * 16 + l15) * SEQ + key0 + ks * 32 + quad * 8;
        o[dt] = __builtin_amdgcn_mfma_f32_16x16x32_f16(pa, *(const f16x8*)vp, o[dt], 0, 0, 0);
      }
    }
  }
#pragma unroll
  for (int dt = 0; dt < 4; dt++)
#pragma unroll
    for (int r = 0; r < 4; r++) {
      int qrow = qr0 + quad * 4 + r;
      out[(size_t)(b * SEQ + qrow) * HS + dt * 16 + l15] = o[dt][r] / l[r];
    }
}

extern "C" void kernel_launch(void* const* d_in, const int* in_sizes, int n_in,
                              void* d_out, int out_size, void* d_ws, size_t ws_size,
                              hipStream_t stream) {
  const float* x  = (const float*)d_in[0];
  const float* Wk = (const float*)d_in[1];
  const float* Wq = (const float*)d_in[2];
  const float* Wv = (const float*)d_in[3];
  float* out = (float*)d_out;

  f16* wpk = (f16*)d_ws;
  f16* qb  = (f16*)((char*)d_ws + OFF_Q);
  f16* kbf = (f16*)((char*)d_ws + OFF_K);
  f16* vtb = (f16*)((char*)d_ws + OFF_VT);
  f16* opart = (f16*)((char*)d_ws + OFF_OP);
  float* ml = (float*)((char*)d_ws + OFF_ML);

  pack_w<<<dim3(72), dim3(256), 0, stream>>>(Wk, Wq, Wv, wpk);
  proj<<<dim3(NTOK / 16), dim3(256), 0, stream>>>(x, (const f16x8*)wpk, qb, kbf, vtb);
  if (ws_size >= (size_t)WS_NEED) {
    attn_part<<<dim3(288, NB), dim3(256), 0, stream>>>(qb, kbf, vtb, opart, ml);
    attn_combine<<<dim3(256), dim3(256), 0, stream>>>(opart, ml, out);
  } else {
    attn_mono<<<dim3(SEQ / 64, NB), dim3(256), 0, stream>>>(qb, kbf, vtb, out);
  }
}

// Round 3
// 192.824 us; speedup vs baseline: 1.4554x; 1.0252x over previous
//
#include <hip/hip_runtime.h>

typedef _Float16 f16;
typedef f16 f16x4 __attribute__((ext_vector_type(4)));
typedef f16 f16x8 __attribute__((ext_vector_type(8)));
typedef float f32x4 __attribute__((ext_vector_type(4)));

#define N_EMBD 768
#define HS 64
#define NB 4
#define SEQ 4096
#define NTOK (NB * SEQ)
#define KSTEPS (N_EMBD / 32)   // 24

// ws layout (bytes)
#define OFF_Q  (3 * KSTEPS * 4 * 64 * 16)        // packed weights: 294912
#define OFF_K  (OFF_Q + NTOK * HS * 2)
#define OFF_VT (OFF_K + NTOK * HS * 2)
#define OFF_OP (OFF_VT + NTOK * HS * 2)          // partial O fp16: 256*8*4096*2
#define OFF_ML (OFF_OP + 256 * 8 * 4096 * 2)     // m,l fp32: 256*8*128*4
#define WS_NEED (OFF_ML + 256 * 8 * 128 * 4)     // ~24.4 MB

// ---------------------------------------------------------------------------
// Pack Wq/Wk/Wv (fp32 [768][64]) into MFMA B-fragment order, fp16.
// B[k=quad*8+j][n=lane&15]; packed idx = ((mu*KSTEPS+ks)*4+ct)*64+lane.
// Scale 1/8 folded into Wq (exact).
// ---------------------------------------------------------------------------
__global__ __launch_bounds__(256) void pack_w(const float* __restrict__ Wk,
                                              const float* __restrict__ Wq,
                                              const float* __restrict__ Wv,
                                              f16* __restrict__ wpk) {
  int tid = blockIdx.x * 256 + threadIdx.x;      // 72*256 = 18432 exactly
  int mu = tid / (KSTEPS * 256);
  int rem = tid % (KSTEPS * 256);
  int kstep = rem >> 8;
  int ct = (rem >> 6) & 3;
  int lane = rem & 63;
  int col = ct * 16 + (lane & 15);
  int k0 = kstep * 32 + (lane >> 4) * 8;
  const float* src = (mu == 0) ? Wq : ((mu == 1) ? Wk : Wv);
  float scale = (mu == 0) ? 0.125f : 1.0f;
  f16x8 v;
#pragma unroll
  for (int j = 0; j < 8; j++) v[j] = (f16)(src[(k0 + j) * HS + col] * scale);
  *((f16x8*)wpk + tid) = v;
}

// ---------------------------------------------------------------------------
// QKV projection, N-split: block = 16 tokens, 4 waves; wave w owns 3 of the
// 12 output tiles (q0..3,k0..3,v0..3) over the FULL K — no reduction.
// x staged via fully-coalesced float4 loads -> fp16 LDS tile (row stride
// 776 f16 = 1552 B: 16B-aligned for b128, bank-clean). Grid 1024 blocks,
// 24 waves/CU LDS capacity -> all resident.
// ---------------------------------------------------------------------------
__global__ __launch_bounds__(256) void proj(const float* __restrict__ x,
                                            const f16x8* __restrict__ wpk,
                                            f16* __restrict__ qb,
                                            f16* __restrict__ kb,
                                            f16* __restrict__ vtb) {
  __shared__ __align__(16) f16 xt[16][776];      // 24832 B
  int t = threadIdx.x;
  int w = t >> 6, lane = t & 63, l15 = lane & 15, quad = lane >> 4;
  int r0 = blockIdx.x * 16;
  const float* xbase = x + (size_t)r0 * N_EMBD;
#pragma unroll
  for (int i = 0; i < 12; i++) {
    int f = i * 256 + t;                         // float4 index, contiguous
    f32x4 v = *(const f32x4*)(xbase + (size_t)f * 4);
    int row = f / 192, cf = f - row * 192;
    f16x4 h;
#pragma unroll
    for (int j = 0; j < 4; j++) h[j] = (f16)v[j];
    *(f16x4*)&xt[row][cf * 4] = h;
  }
  __syncthreads();

  f32x4 acc[3];
#pragma unroll
  for (int i = 0; i < 3; i++) acc[i] = (f32x4)0.0f;
  int j0 = w * 3;
  for (int ks = 0; ks < KSTEPS; ks++) {
    f16x8 af = *(const f16x8*)&xt[l15][ks * 32 + quad * 8];
#pragma unroll
    for (int jj = 0; jj < 3; jj++) {
      int j = j0 + jj, mu = j >> 2, ct = j & 3;
      f16x8 bf = wpk[((mu * KSTEPS + ks) * 4 + ct) * 64 + lane];
      acc[jj] = __builtin_amdgcn_mfma_f32_16x16x32_f16(af, bf, acc[jj], 0, 0, 0);
    }
  }
  // C/D layout: col = l15, row = quad*4 + reg
#pragma unroll
  for (int jj = 0; jj < 3; jj++) {
    int j = j0 + jj, mu = j >> 2, ct = j & 3;
    int col = ct * 16 + l15;
    if (mu < 2) {
      f16* dst = mu ? kb : qb;
#pragma unroll
      for (int reg = 0; reg < 4; reg++)
        dst[(r0 + quad * 4 + reg) * HS + col] = (f16)acc[jj][reg];
    } else {
#pragma unroll
      for (int reg = 0; reg < 4; reg++) {
        int row = r0 + quad * 4 + reg;
        vtb[(((row >> 12) * HS + col) << 12) + (row & (SEQ - 1))] = (f16)acc[jj][reg];
      }
    }
  }
}

// ---------------------------------------------------------------------------
// Flash attention partials, S^T formulation: sc = K·Q^T so C col = q-row.
// Each lane owns ONE q-row: softmax = in-register reduce over 16 scores +
// 2 shuffles (xor16/xor32); m,l,alpha are lane scalars. PV as O^T = V^T·P^T;
// P^T -> B-frag via 4 ds_write_b64 + 2 ds_read_b128 (wave-private LDS).
// ---------------------------------------------------------------------------
__global__ __launch_bounds__(256) void attn_part(const f16* __restrict__ qb,
                                                 const f16* __restrict__ kb,
                                                 const f16* __restrict__ vtb,
                                                 f16* __restrict__ opart,
                                                 float* __restrict__ ml) {
  __shared__ __align__(16) f16 pbuf[4][16][72];  // row stride 144 B (16B mult)
  int w = threadIdx.x >> 6, lane = threadIdx.x & 63;
  int l15 = lane & 15, quad = lane >> 4;
  int p = blockIdx.x, b = blockIdx.y;
  int g = 0;
  while (p >= 4 * (g + 1) * (g + 2)) g++;        // group g: qt in [8g, 8g+8)
  int rem = p - 4 * g * (g + 1);
  int j = rem / (g + 1);
  int s = rem - j * (g + 1);
  int qt = 8 * g + j;
  int kb_beg = s * 8;
  int kb_end = (s * 8 + 8 < qt + 1) ? (s * 8 + 8) : (qt + 1);

  int qr0 = qt * 64 + w * 16;
  int gq = b * SEQ + qr0;
  int qrow = qr0 + l15;                          // this lane's q-row

  f16x8 qa[2];
  {
    const f16* qrp = qb + (size_t)(gq + l15) * HS + quad * 8;
    qa[0] = *(const f16x8*)(qrp);
    qa[1] = *(const f16x8*)(qrp + 32);
  }

  f32x4 o[4];
#pragma unroll
  for (int i = 0; i < 4; i++) o[i] = (f32x4)0.0f;
  float m = -INFINITY, l = 0.0f;

  const f16* kb_b = kb + (size_t)b * SEQ * HS;
  const f16* vt_b = vtb + (size_t)b * HS * SEQ;

  for (int kbk = kb_beg; kbk < kb_end; kbk++) {
    int key0 = kbk * 64;
    // S^T = K Q^T: A-frag = K rows (contig 16B), B-frag = qa.
    f32x4 sc[4];
#pragma unroll
    for (int kt = 0; kt < 4; kt++) sc[kt] = (f32x4)0.0f;
#pragma unroll
    for (int ks = 0; ks < 2; ks++) {
#pragma unroll
      for (int kt = 0; kt < 4; kt++) {
        const f16* kp = kb_b + (size_t)(key0 + kt * 16 + l15) * HS + ks * 32 + quad * 8;
        f16x8 kfr = *(const f16x8*)kp;
        sc[kt] = __builtin_amdgcn_mfma_f32_16x16x32_f16(kfr, qa[ks], sc[kt], 0, 0, 0);
      }
    }
    // causal mask (diagonal block only): C row = key_local = quad*4+reg
    if (kbk == qt) {
#pragma unroll
      for (int kt = 0; kt < 4; kt++) {
        int keyb = key0 + kt * 16 + quad * 4;
#pragma unroll
        for (int reg = 0; reg < 4; reg++)
          if (keyb + reg > qrow) sc[kt][reg] = -INFINITY;
      }
    }
    // per-lane softmax over this lane's 16 scores, then 2 cross-quad shuffles
    float mx;
    {
      float a0 = fmaxf(fmaxf(sc[0][0], sc[0][1]), fmaxf(sc[0][2], sc[0][3]));
      float a1 = fmaxf(fmaxf(sc[1][0], sc[1][1]), fmaxf(sc[1][2], sc[1][3]));
      float a2 = fmaxf(fmaxf(sc[2][0], sc[2][1]), fmaxf(sc[2][2], sc[2][3]));
      float a3 = fmaxf(fmaxf(sc[3][0], sc[3][1]), fmaxf(sc[3][2], sc[3][3]));
      mx = fmaxf(fmaxf(a0, a1), fmaxf(a2, a3));
    }
    mx = fmaxf(mx, __shfl_xor(mx, 16, 64));
    mx = fmaxf(mx, __shfl_xor(mx, 32, 64));
    float mn = fmaxf(m, mx);
    float alpha = __expf(m - mn);
    m = mn;
    float pv[4][4];
    float sum = 0.0f;
#pragma unroll
    for (int kt = 0; kt < 4; kt++) {
      float s0 = __expf(sc[kt][0] - mn), s1 = __expf(sc[kt][1] - mn);
      float s2 = __expf(sc[kt][2] - mn), s3 = __expf(sc[kt][3] - mn);
      pv[kt][0] = s0; pv[kt][1] = s1; pv[kt][2] = s2; pv[kt][3] = s3;
      sum += (s0 + s1) + (s2 + s3);
    }
    sum += __shfl_xor(sum, 16, 64);
    sum += __shfl_xor(sum, 32, 64);
    l = l * alpha + sum;
#pragma unroll
    for (int dt = 0; dt < 4; dt++) o[dt] *= alpha;

    // P^T -> LDS [qrow][key]: regs are 4 consecutive keys -> one b64 per kt
#pragma unroll
    for (int kt = 0; kt < 4; kt++) {
      f16x4 h;
#pragma unroll
      for (int reg = 0; reg < 4; reg++) h[reg] = (f16)pv[kt][reg];
      *(f16x4*)&pbuf[w][l15][kt * 16 + quad * 4] = h;
    }
    // O^T += V^T P^T
#pragma unroll
    for (int ks = 0; ks < 2; ks++) {
      f16x8 pf = *(const f16x8*)&pbuf[w][l15][ks * 32 + quad * 8];
#pragma unroll
      for (int dt = 0; dt < 4; dt++) {
        const f16* vp = vt_b + (size_t)(dt * 16 + l15) * SEQ + key0 + ks * 32 + quad * 8;
        f16x8 vfr = *(const f16x8*)vp;
        o[dt] = __builtin_amdgcn_mfma_f32_16x16x32_f16(vfr, pf, o[dt], 0, 0, 0);
      }
    }
  }
  // store partials: O^T C-layout: dim = dt*16+quad*4+reg, qrow = w*16+l15
  int slot = (b * 64 + qt) * 8 + s;
  f16* op = opart + (size_t)slot * 4096;
#pragma unroll
  for (int dt = 0; dt < 4; dt++) {
    f16x4 h;
#pragma unroll
    for (int reg = 0; reg < 4; reg++) h[reg] = (f16)o[dt][reg];
    *(f16x4*)&op[(w * 16 + l15) * 64 + dt * 16 + quad * 4] = h;
  }
  if (quad == 0) {
    ml[slot * 128 + w * 16 + l15] = m;
    ml[slot * 128 + 64 + w * 16 + l15] = l;
  }
}

// ---------------------------------------------------------------------------
// Combine: 512 blocks (one per (b, qt, row-half)), thread = (row, 8-dim chunk).
// ---------------------------------------------------------------------------
__global__ __launch_bounds__(256) void attn_combine(const f16* __restrict__ opart,
                                                    const float* __restrict__ ml,
                                                    float* __restrict__ out) {
  int blk = blockIdx.x;
  int h = blk & 1, bq = blk >> 1;
  int b = bq >> 6, qt = bq & 63;
  int nseg = (qt >> 3) + 1;
  int tid = threadIdx.x;
  int r = h * 32 + (tid >> 3), d0 = (tid & 7) * 8;
  int base_slot = (b * 64 + qt) * 8;

  float M = -INFINITY;
  for (int s = 0; s < nseg; s++) M = fmaxf(M, ml[(base_slot + s) * 128 + r]);
  float L = 0.0f;
  for (int s = 0; s < nseg; s++) {
    float e = __expf(ml[(base_slot + s) * 128 + r] - M);
    L += ml[(base_slot + s) * 128 + 64 + r] * e;
  }
  float acc[8];
#pragma unroll
  for (int i = 0; i < 8; i++) acc[i] = 0.0f;
  for (int s = 0; s < nseg; s++) {
    float e = __expf(ml[(base_slot + s) * 128 + r] - M);
    f16x8 a = *(const f16x8*)(opart + (size_t)(base_slot + s) * 4096 + r * 64 + d0);
#pragma unroll
    for (int i = 0; i < 8; i++) acc[i] += e * (float)a[i];
  }
  float inv = 1.0f / L;
  float* po = out + ((size_t)(b * SEQ + qt * 64 + r)) * HS + d0;
#pragma unroll
  for (int i = 0; i < 8; i++) po[i] = acc[i] * inv;
}

// ---------------------------------------------------------------------------
// Fallback monolithic attention (used only if ws_size < WS_NEED).
// ---------------------------------------------------------------------------
__global__ __launch_bounds__(256) void attn_mono(const f16* __restrict__ qb,
                                                 const f16* __restrict__ kb,
                                                 const f16* __restrict__ vtb,
                                                 float* __restrict__ out) {
  __shared__ __align__(16) f16 pbuf[4][16][72];
  int w = threadIdx.x >> 6, lane = threadIdx.x & 63;
  int l15 = lane & 15, quad = lane >> 4;
  int qt = blockIdx.x, b = blockIdx.y;
  int qr0 = qt * 64 + w * 16;
  int gq = b * SEQ + qr0;
  int qrow = qr0 + l15;
  f16x8 qa[2];
  {
    const f16* qrp = qb + (size_t)(gq + l15) * HS + quad * 8;
    qa[0] = *(const f16x8*)(qrp);
    qa[1] = *(const f16x8*)(qrp + 32);
  }
  f32x4 o[4];
#pragma unroll
  for (int i = 0; i < 4; i++) o[i] = (f32x4)0.0f;
  float m = -INFINITY, l = 0.0f;
  const f16* kb_b = kb + (size_t)b * SEQ * HS;
  const f16* vt_b = vtb + (size_t)b * HS * SEQ;
  for (int kbk = 0; kbk <= qt; kbk++) {
    int key0 = kbk * 64;
    f32x4 sc[4];
#pragma unroll
    for (int kt = 0; kt < 4; kt++) sc[kt] = (f32x4)0.0f;
#pragma unroll
    for (int ks = 0; ks < 2; ks++)
#pragma unroll
      for (int kt = 0; kt < 4; kt++) {
        const f16* kp = kb_b + (size_t)(key0 + kt * 16 + l15) * HS + ks * 32 + quad * 8;
        sc[kt] = __builtin_amdgcn_mfma_f32_16x16x32_f16(*(const f16x8*)kp, qa[ks], sc[kt], 0, 0, 0);
      }
    if (kbk == qt) {
#pragma unroll
      for (int kt = 0; kt < 4; kt++) {
        int keyb = key0 + kt * 16 + quad * 4;
#pragma unroll
        for (int reg = 0; reg < 4; reg++)
          if (keyb + reg > qrow) sc[kt][reg] = -INFINITY;
      }
    }
    float mx;
    {
      float a0 = fmaxf(fmaxf(sc[0][0], sc[0][1]), fmaxf(sc[0][2], sc[0][3]));
      float a1 = fmaxf(fmaxf(sc[1][0], sc[1][1]), fmaxf(sc[1][2], sc[1][3]));
      float a2 = fmaxf(fmaxf(sc[2][0], sc[2][1]), fmaxf(sc[2][2], sc[2][3]));
      float a3 = fmaxf(fmaxf(sc[3][0], sc[3][1]), fmaxf(sc[3][2], sc[3][3]));
      mx = fmaxf(fmaxf(a0, a1), fmaxf(a2, a3));
    }
    mx = fmaxf(mx, __shfl_xor(mx, 16, 64));
    mx = fmaxf(mx, __shfl_xor(mx, 32, 64));
    float mn = fmaxf(m, mx);
    float alpha = __expf(m - mn);
    m = mn;
    float pv[4][4];
    float sum = 0.0f;
#pragma unroll
    for (int kt = 0; kt < 4; kt++) {
      float s0 = __expf(sc[kt][0] - mn), s1 = __expf(sc[kt][1] - mn);
      float s2 = __expf(sc[kt][2] - mn), s3 = __expf(sc[kt][3] - mn);
      pv[kt][0] = s0; pv[kt][1] = s1; pv[kt][2] = s2; pv[kt][3] = s3;
      sum += (s0 + s1) + (s2 + s3);
    }
    sum += __shfl_xor(sum, 16, 64);
    sum += __shfl_xor(sum, 32, 64);
    l = l * alpha + sum;
#pragma unroll
    for (int dt = 0; dt < 4; dt++) o[dt] *= alpha;
#pragma unroll
    for (int kt = 0; kt < 4; kt++) {
      f16x4 hh;
#pragma unroll
      for (int reg = 0; reg < 4; reg++) hh[reg] = (f16)pv[kt][reg];
      *(f16x4*)&pbuf[w][l15][kt * 16 + quad * 4] = hh;
    }
#pragma unroll
    for (int ks = 0; ks < 2; ks++) {
      f16x8 pf = *(const f16x8*)&pbuf[w][l15][ks * 32 + quad * 8];
#pragma unroll
      for (int dt = 0; dt < 4; dt++) {
        const f16* vp = vt_b + (size_t)(dt * 16 + l15) * SEQ + key0 + ks * 32 + quad * 8;
        o[dt] = __builtin_amdgcn_mfma_f32_16x16x32_f16(*(const f16x8*)vp, pf, o[dt], 0, 0, 0);
      }
    }
  }
  float inv = 1.0f / l;
#pragma unroll
  for (int dt = 0; dt < 4; dt++)
#pragma unroll
    for (int reg = 0; reg < 4; reg++)
      out[(size_t)(b * SEQ + qr0 + l15) * HS + dt * 16 + quad * 4 + reg] = o[dt][reg] * inv;
}

extern "C" void kernel_launch(void* const* d_in, const int* in_sizes, int n_in,
                              void* d_out, int out_size, void* d_ws, size_t ws_size,
                              hipStream_t stream) {
  const float* x  = (const float*)d_in[0];
  const float* Wk = (const float*)d_in[1];
  const float* Wq = (const float*)d_in[2];
  const float* Wv = (const float*)d_in[3];
  float* out = (float*)d_out;

  f16* wpk = (f16*)d_ws;
  f16* qb  = (f16*)((char*)d_ws + OFF_Q);
  f16* kbf = (f16*)((char*)d_ws + OFF_K);
  f16* vtb = (f16*)((char*)d_ws + OFF_VT);
  f16* opart = (f16*)((char*)d_ws + OFF_OP);
  float* ml = (float*)((char*)d_ws + OFF_ML);

  pack_w<<<dim3(72), dim3(256), 0, stream>>>(Wk, Wq, Wv, wpk);
  proj<<<dim3(NTOK / 16), dim3(256), 0, stream>>>(x, (const f16x8*)wpk, qb, kbf, vtb);
  if (ws_size >= (size_t)WS_NEED) {
    attn_part<<<dim3(288, NB), dim3(256), 0, stream>>>(qb, kbf, vtb, opart, ml);
    attn_combine<<<dim3(512), dim3(256), 0, stream>>>(opart, ml, out);
  } else {
    attn_mono<<<dim3(SEQ / 64, NB), dim3(256), 0, stream>>>(qb, kbf, vtb, out);
  }
}

// Round 4
// 179.340 us; speedup vs baseline: 1.5648x; 1.0752x over previous
//
#include <hip/hip_runtime.h>

typedef _Float16 f16;
typedef f16 f16x4 __attribute__((ext_vector_type(4)));
typedef f16 f16x8 __attribute__((ext_vector_type(8)));
typedef float f32x4 __attribute__((ext_vector_type(4)));

#define N_EMBD 768
#define HS 64
#define NB 4
#define SEQ 4096
#define NTOK (NB * SEQ)
#define KSTEPS (N_EMBD / 32)   // 24

// ws layout (bytes)
#define OFF_Q  (3 * KSTEPS * 4 * 64 * 16)        // packed weights: 294912
#define OFF_K  (OFF_Q + NTOK * HS * 2)
#define OFF_VT (OFF_K + NTOK * HS * 2)
#define OFF_OP (OFF_VT + NTOK * HS * 2)          // partial O fp16: 256*8*4096*2
#define OFF_ML (OFF_OP + 256 * 8 * 4096 * 2)     // m,l fp32: 256*8*128*4
#define WS_NEED (OFF_ML + 256 * 8 * 128 * 4)     // ~24.4 MB

// ---------------------------------------------------------------------------
// Pack Wq/Wk/Wv (fp32 [768][64]) into MFMA B-fragment order, fp16.
// ---------------------------------------------------------------------------
__global__ __launch_bounds__(256) void pack_w(const float* __restrict__ Wk,
                                              const float* __restrict__ Wq,
                                              const float* __restrict__ Wv,
                                              f16* __restrict__ wpk) {
  int tid = blockIdx.x * 256 + threadIdx.x;      // 72*256 = 18432 exactly
  int mu = tid / (KSTEPS * 256);
  int rem = tid % (KSTEPS * 256);
  int kstep = rem >> 8;
  int ct = (rem >> 6) & 3;
  int lane = rem & 63;
  int col = ct * 16 + (lane & 15);
  int k0 = kstep * 32 + (lane >> 4) * 8;
  const float* src = (mu == 0) ? Wq : ((mu == 1) ? Wk : Wv);
  float scale = (mu == 0) ? 0.125f : 1.0f;
  float t0[8];
#pragma unroll
  for (int j = 0; j < 8; j++) t0[j] = src[(k0 + j) * HS + col];  // batched loads
  f16x8 v;
#pragma unroll
  for (int j = 0; j < 8; j++) v[j] = (f16)(t0[j] * scale);
  *((f16x8*)wpk + tid) = v;
}

// ---------------------------------------------------------------------------
// QKV projection, N-split, batched loads: block = 16 tokens, 4 waves; wave w
// owns 3 of 12 output tiles over full K. K-loop unrolled x2 so each waitcnt
// region covers 2 ds_read_b128 + 6 global 16B loads (MLP, not serial chains).
// ---------------------------------------------------------------------------
__global__ __launch_bounds__(256) void proj(const float* __restrict__ x,
                                            const f16x8* __restrict__ wpk,
                                            f16* __restrict__ qb,
                                            f16* __restrict__ kb,
                                            f16* __restrict__ vtb) {
  __shared__ __align__(16) f16 xt[16][776];      // 24832 B
  int t = threadIdx.x;
  int w = t >> 6, lane = t & 63, l15 = lane & 15, quad = lane >> 4;
  int r0 = blockIdx.x * 16;
  const float* xbase = x + (size_t)r0 * N_EMBD;
  {
    f32x4 v[12];
#pragma unroll
    for (int i = 0; i < 12; i++)
      v[i] = *(const f32x4*)(xbase + (size_t)(i * 256 + t) * 4);   // 12 batched
#pragma unroll
    for (int i = 0; i < 12; i++) {
      int f = i * 256 + t;
      int row = f / 192, cf = f - row * 192;
      f16x4 h;
#pragma unroll
      for (int j = 0; j < 4; j++) h[j] = (f16)v[i][j];
      *(f16x4*)&xt[row][cf * 4] = h;
    }
  }
  __syncthreads();

  f32x4 acc[3];
#pragma unroll
  for (int i = 0; i < 3; i++) acc[i] = (f32x4)0.0f;
  int j0 = w * 3;
  int mu0 = (j0 + 0) >> 2, ct0 = (j0 + 0) & 3;
  int mu1 = (j0 + 1) >> 2, ct1 = (j0 + 1) & 3;
  int mu2 = (j0 + 2) >> 2, ct2 = (j0 + 2) & 3;
  for (int ks = 0; ks < KSTEPS; ks += 2) {
    f16x8 af0 = *(const f16x8*)&xt[l15][ks * 32 + quad * 8];
    f16x8 af1 = *(const f16x8*)&xt[l15][ks * 32 + 32 + quad * 8];
    f16x8 b00 = wpk[((mu0 * KSTEPS + ks) * 4 + ct0) * 64 + lane];
    f16x8 b01 = wpk[((mu1 * KSTEPS + ks) * 4 + ct1) * 64 + lane];
    f16x8 b02 = wpk[((mu2 * KSTEPS + ks) * 4 + ct2) * 64 + lane];
    f16x8 b10 = wpk[((mu0 * KSTEPS + ks + 1) * 4 + ct0) * 64 + lane];
    f16x8 b11 = wpk[((mu1 * KSTEPS + ks + 1) * 4 + ct1) * 64 + lane];
    f16x8 b12 = wpk[((mu2 * KSTEPS + ks + 1) * 4 + ct2) * 64 + lane];
    acc[0] = __builtin_amdgcn_mfma_f32_16x16x32_f16(af0, b00, acc[0], 0, 0, 0);
    acc[1] = __builtin_amdgcn_mfma_f32_16x16x32_f16(af0, b01, acc[1], 0, 0, 0);
    acc[2] = __builtin_amdgcn_mfma_f32_16x16x32_f16(af0, b02, acc[2], 0, 0, 0);
    acc[0] = __builtin_amdgcn_mfma_f32_16x16x32_f16(af1, b10, acc[0], 0, 0, 0);
    acc[1] = __builtin_amdgcn_mfma_f32_16x16x32_f16(af1, b11, acc[1], 0, 0, 0);
    acc[2] = __builtin_amdgcn_mfma_f32_16x16x32_f16(af1, b12, acc[2], 0, 0, 0);
  }
  // C/D layout: col = l15, row = quad*4 + reg
#pragma unroll
  for (int jj = 0; jj < 3; jj++) {
    int j = j0 + jj, mu = j >> 2, ct = j & 3;
    int col = ct * 16 + l15;
    if (mu < 2) {
      f16* dst = mu ? kb : qb;
#pragma unroll
      for (int reg = 0; reg < 4; reg++)
        dst[(r0 + quad * 4 + reg) * HS + col] = (f16)acc[jj][reg];
    } else {
#pragma unroll
      for (int reg = 0; reg < 4; reg++) {
        int row = r0 + quad * 4 + reg;
        vtb[(((row >> 12) * HS + col) << 12) + (row & (SEQ - 1))] = (f16)acc[jj][reg];
      }
    }
  }
}

// ---------------------------------------------------------------------------
// Flash attention partials, S^T formulation, MLP-batched loads:
// all 8 K-frags loaded into SSA regs before the S-MFMAs (one waitcnt, 8
// parallel loads); all 8 V-frags issued BEFORE softmax so the ~500cy of
// exp/max covers their latency. Longest segments launch first (287-p).
// ---------------------------------------------------------------------------
__global__ __launch_bounds__(256) void attn_part(const f16* __restrict__ qb,
                                                 const f16* __restrict__ kb,
                                                 const f16* __restrict__ vtb,
                                                 f16* __restrict__ opart,
                                                 float* __restrict__ ml) {
  __shared__ __align__(16) f16 pbuf[4][16][72];
  int w = threadIdx.x >> 6, lane = threadIdx.x & 63;
  int l15 = lane & 15, quad = lane >> 4;
  int p = 287 - blockIdx.x, b = blockIdx.y;      // longest (big g) first
  int g = 0;
  while (p >= 4 * (g + 1) * (g + 2)) g++;        // group g: qt in [8g, 8g+8)
  int rem = p - 4 * g * (g + 1);
  int j = rem / (g + 1);
  int s = rem - j * (g + 1);
  int qt = 8 * g + j;
  int kb_beg = s * 8;
  int kb_end = (s * 8 + 8 < qt + 1) ? (s * 8 + 8) : (qt + 1);

  int qr0 = qt * 64 + w * 16;
  int gq = b * SEQ + qr0;
  int qrow = qr0 + l15;                          // this lane's q-row

  f16x8 qa[2];
  {
    const f16* qrp = qb + (size_t)(gq + l15) * HS + quad * 8;
    qa[0] = *(const f16x8*)(qrp);
    qa[1] = *(const f16x8*)(qrp + 32);
  }

  f32x4 o[4];
#pragma unroll
  for (int i = 0; i < 4; i++) o[i] = (f32x4)0.0f;
  float m = -INFINITY, l = 0.0f;

  const f16* kb_b = kb + (size_t)b * SEQ * HS;
  const f16* vt_b = vtb + (size_t)b * HS * SEQ;

  for (int kbk = kb_beg; kbk < kb_end; kbk++) {
    int key0 = kbk * 64;
    // ---- batched K-fragment loads (8 independent) ----
    f16x8 kf[2][4];
#pragma unroll
    for (int ks = 0; ks < 2; ks++)
#pragma unroll
      for (int kt = 0; kt < 4; kt++)
        kf[ks][kt] = *(const f16x8*)(kb_b +
            (size_t)(key0 + kt * 16 + l15) * HS + ks * 32 + quad * 8);
    // ---- S^T = K Q^T ----
    f32x4 sc[4];
#pragma unroll
    for (int kt = 0; kt < 4; kt++) sc[kt] = (f32x4)0.0f;
#pragma unroll
    for (int ks = 0; ks < 2; ks++)
#pragma unroll
      for (int kt = 0; kt < 4; kt++)
        sc[kt] = __builtin_amdgcn_mfma_f32_16x16x32_f16(kf[ks][kt], qa[ks], sc[kt], 0, 0, 0);
    // ---- issue V loads NOW (independent of softmax; latency hidden) ----
    f16x8 vf[2][4];
#pragma unroll
    for (int ks = 0; ks < 2; ks++)
#pragma unroll
      for (int dt = 0; dt < 4; dt++)
        vf[ks][dt] = *(const f16x8*)(vt_b +
            (size_t)(dt * 16 + l15) * SEQ + key0 + ks * 32 + quad * 8);
    // ---- causal mask (diagonal block only): C row = key_local ----
    if (kbk == qt) {
#pragma unroll
      for (int kt = 0; kt < 4; kt++) {
        int keyb = key0 + kt * 16 + quad * 4;
#pragma unroll
        for (int reg = 0; reg < 4; reg++)
          if (keyb + reg > qrow) sc[kt][reg] = -INFINITY;
      }
    }
    // ---- per-lane softmax (16 scores) + 2 cross-half shuffles ----
    float mx;
    {
      float a0 = fmaxf(fmaxf(sc[0][0], sc[0][1]), fmaxf(sc[0][2], sc[0][3]));
      float a1 = fmaxf(fmaxf(sc[1][0], sc[1][1]), fmaxf(sc[1][2], sc[1][3]));
      float a2 = fmaxf(fmaxf(sc[2][0], sc[2][1]), fmaxf(sc[2][2], sc[2][3]));
      float a3 = fmaxf(fmaxf(sc[3][0], sc[3][1]), fmaxf(sc[3][2], sc[3][3]));
      mx = fmaxf(fmaxf(a0, a1), fmaxf(a2, a3));
    }
    mx = fmaxf(mx, __shfl_xor(mx, 16, 64));
    mx = fmaxf(mx, __shfl_xor(mx, 32, 64));
    float mn = fmaxf(m, mx);
    float alpha = __expf(m - mn);
    m = mn;
    float pv[4][4];
    float sum = 0.0f;
#pragma unroll
    for (int kt = 0; kt < 4; kt++) {
      float s0 = __expf(sc[kt][0] - mn), s1 = __expf(sc[kt][1] - mn);
      float s2 = __expf(sc[kt][2] - mn), s3 = __expf(sc[kt][3] - mn);
      pv[kt][0] = s0; pv[kt][1] = s1; pv[kt][2] = s2; pv[kt][3] = s3;
      sum += (s0 + s1) + (s2 + s3);
    }
    sum += __shfl_xor(sum, 16, 64);
    sum += __shfl_xor(sum, 32, 64);
    l = l * alpha + sum;
#pragma unroll
    for (int dt = 0; dt < 4; dt++) o[dt] *= alpha;

    // ---- P^T -> LDS (wave-private, regs = 4 consecutive keys -> b64) ----
#pragma unroll
    for (int kt = 0; kt < 4; kt++) {
      f16x4 h;
#pragma unroll
      for (int reg = 0; reg < 4; reg++) h[reg] = (f16)pv[kt][reg];
      *(f16x4*)&pbuf[w][l15][kt * 16 + quad * 4] = h;
    }
    // ---- O^T += V^T P^T ----
#pragma unroll
    for (int ks = 0; ks < 2; ks++) {
      f16x8 pf = *(const f16x8*)&pbuf[w][l15][ks * 32 + quad * 8];
#pragma unroll
      for (int dt = 0; dt < 4; dt++)
        o[dt] = __builtin_amdgcn_mfma_f32_16x16x32_f16(vf[ks][dt], pf, o[dt], 0, 0, 0);
    }
  }
  // store partials: dim = dt*16+quad*4+reg, qrow = w*16+l15
  int slot = (b * 64 + qt) * 8 + s;
  f16* op = opart + (size_t)slot * 4096;
#pragma unroll
  for (int dt = 0; dt < 4; dt++) {
    f16x4 h;
#pragma unroll
    for (int reg = 0; reg < 4; reg++) h[reg] = (f16)o[dt][reg];
    *(f16x4*)&op[(w * 16 + l15) * 64 + dt * 16 + quad * 4] = h;
  }
  if (quad == 0) {
    ml[slot * 128 + w * 16 + l15] = m;
    ml[slot * 128 + 64 + w * 16 + l15] = l;
  }
}

// ---------------------------------------------------------------------------
// Combine: 512 blocks; batched segment loads (all <=8 segs issued together).
// ---------------------------------------------------------------------------
__global__ __launch_bounds__(256) void attn_combine(const f16* __restrict__ opart,
                                                    const float* __restrict__ ml,
                                                    float* __restrict__ out) {
  int blk = blockIdx.x;
  int h = blk & 1, bq = blk >> 1;
  int b = bq >> 6, qt = bq & 63;
  int nseg = (qt >> 3) + 1;
  int tid = threadIdx.x;
  int r = h * 32 + (tid >> 3), d0 = (tid & 7) * 8;
  int base_slot = (b * 64 + qt) * 8;

  float mv[8], lv[8];
#pragma unroll
  for (int s = 0; s < 8; s++) {
    if (s < nseg) {
      mv[s] = ml[(base_slot + s) * 128 + r];
      lv[s] = ml[(base_slot + s) * 128 + 64 + r];
    } else { mv[s] = -INFINITY; lv[s] = 0.0f; }
  }
  float M = -INFINITY;
#pragma unroll
  for (int s = 0; s < 8; s++) M = fmaxf(M, mv[s]);
  float e[8], L = 0.0f;
#pragma unroll
  for (int s = 0; s < 8; s++) { e[s] = __expf(mv[s] - M); L += lv[s] * e[s]; }
  float acc[8];
#pragma unroll
  for (int i = 0; i < 8; i++) acc[i] = 0.0f;
  for (int s = 0; s < nseg; s++) {
    f16x8 a = *(const f16x8*)(opart + (size_t)(base_slot + s) * 4096 + r * 64 + d0);
#pragma unroll
    for (int i = 0; i < 8; i++) acc[i] += e[s] * (float)a[i];
  }
  float inv = 1.0f / L;
  float* po = out + ((size_t)(b * SEQ + qt * 64 + r)) * HS + d0;
#pragma unroll
  for (int i = 0; i < 8; i++) po[i] = acc[i] * inv;
}

// ---------------------------------------------------------------------------
// Fallback monolithic attention (used only if ws_size < WS_NEED).
// ---------------------------------------------------------------------------
__global__ __launch_bounds__(256) void attn_mono(const f16* __restrict__ qb,
                                                 const f16* __restrict__ kb,
                                                 const f16* __restrict__ vtb,
                                                 float* __restrict__ out) {
  __shared__ __align__(16) f16 pbuf[4][16][72];
  int w = threadIdx.x >> 6, lane = threadIdx.x & 63;
  int l15 = lane & 15, quad = lane >> 4;
  int qt = blockIdx.x, b = blockIdx.y;
  int qr0 = qt * 64 + w * 16;
  int gq = b * SEQ + qr0;
  int qrow = qr0 + l15;
  f16x8 qa[2];
  {
    const f16* qrp = qb + (size_t)(gq + l15) * HS + quad * 8;
    qa[0] = *(const f16x8*)(qrp);
    qa[1] = *(const f16x8*)(qrp + 32);
  }
  f32x4 o[4];
#pragma unroll
  for (int i = 0; i < 4; i++) o[i] = (f32x4)0.0f;
  float m = -INFINITY, l = 0.0f;
  const f16* kb_b = kb + (size_t)b * SEQ * HS;
  const f16* vt_b = vtb + (size_t)b * HS * SEQ;
  for (int kbk = 0; kbk <= qt; kbk++) {
    int key0 = kbk * 64;
    f16x8 kf[2][4];
#pragma unroll
    for (int ks = 0; ks < 2; ks++)
#pragma unroll
      for (int kt = 0; kt < 4; kt++)
        kf[ks][kt] = *(const f16x8*)(kb_b +
            (size_t)(key0 + kt * 16 + l15) * HS + ks * 32 + quad * 8);
    f32x4 sc[4];
#pragma unroll
    for (int kt = 0; kt < 4; kt++) sc[kt] = (f32x4)0.0f;
#pragma unroll
    for (int ks = 0; ks < 2; ks++)
#pragma unroll
      for (int kt = 0; kt < 4; kt++)
        sc[kt] = __builtin_amdgcn_mfma_f32_16x16x32_f16(kf[ks][kt], qa[ks], sc[kt], 0, 0, 0);
    f16x8 vf[2][4];
#pragma unroll
    for (int ks = 0; ks < 2; ks++)
#pragma unroll
      for (int dt = 0; dt < 4; dt++)
        vf[ks][dt] = *(const f16x8*)(vt_b +
            (size_t)(dt * 16 + l15) * SEQ + key0 + ks * 32 + quad * 8);
    if (kbk == qt) {
#pragma unroll
      for (int kt = 0; kt < 4; kt++) {
        int keyb = key0 + kt * 16 + quad * 4;
#pragma unroll
        for (int reg = 0; reg < 4; reg++)
          if (keyb + reg > qrow) sc[kt][reg] = -INFINITY;
      }
    }
    float mx;
    {
      float a0 = fmaxf(fmaxf(sc[0][0], sc[0][1]), fmaxf(sc[0][2], sc[0][3]));
      float a1 = fmaxf(fmaxf(sc[1][0], sc[1][1]), fmaxf(sc[1][2], sc[1][3]));
      float a2 = fmaxf(fmaxf(sc[2][0], sc[2][1]), fmaxf(sc[2][2], sc[2][3]));
      float a3 = fmaxf(fmaxf(sc[3][0], sc[3][1]), fmaxf(sc[3][2], sc[3][3]));
      mx = fmaxf(fmaxf(a0, a1), fmaxf(a2, a3));
    }
    mx = fmaxf(mx, __shfl_xor(mx, 16, 64));
    mx = fmaxf(mx, __shfl_xor(mx, 32, 64));
    float mn = fmaxf(m, mx);
    float alpha = __expf(m - mn);
    m = mn;
    float pv[4][4];
    float sum = 0.0f;
#pragma unroll
    for (int kt = 0; kt < 4; kt++) {
      float s0 = __expf(sc[kt][0] - mn), s1 = __expf(sc[kt][1] - mn);
      float s2 = __expf(sc[kt][2] - mn), s3 = __expf(sc[kt][3] - mn);
      pv[kt][0] = s0; pv[kt][1] = s1; pv[kt][2] = s2; pv[kt][3] = s3;
      sum += (s0 + s1) + (s2 + s3);
    }
    sum += __shfl_xor(sum, 16, 64);
    sum += __shfl_xor(sum, 32, 64);
    l = l * alpha + sum;
#pragma unroll
    for (int dt = 0; dt < 4; dt++) o[dt] *= alpha;
#pragma unroll
    for (int kt = 0; kt < 4; kt++) {
      f16x4 hh;
#pragma unroll
      for (int reg = 0; reg < 4; reg++) hh[reg] = (f16)pv[kt][reg];
      *(f16x4*)&pbuf[w][l15][kt * 16 + quad * 4] = hh;
    }
#pragma unroll
    for (int ks = 0; ks < 2; ks++) {
      f16x8 pf = *(const f16x8*)&pbuf[w][l15][ks * 32 + quad * 8];
#pragma unroll
      for (int dt = 0; dt < 4; dt++)
        o[dt] = __builtin_amdgcn_mfma_f32_16x16x32_f16(vf[ks][dt], pf, o[dt], 0, 0, 0);
    }
  }
  float inv = 1.0f / l;
#pragma unroll
  for (int dt = 0; dt < 4; dt++)
#pragma unroll
    for (int reg = 0; reg < 4; reg++)
      out[(size_t)(b * SEQ + qr0 + l15) * HS + dt * 16 + quad * 4 + reg] = o[dt][reg] * inv;
}

extern "C" void kernel_launch(void* const* d_in, const int* in_sizes, int n_in,
                              void* d_out, int out_size, void* d_ws, size_t ws_size,
                              hipStream_t stream) {
  const float* x  = (const float*)d_in[0];
  const float* Wk = (const float*)d_in[1];
  const float* Wq = (const float*)d_in[2];
  const float* Wv = (const float*)d_in[3];
  float* out = (float*)d_out;

  f16* wpk = (f16*)d_ws;
  f16* qb  = (f16*)((char*)d_ws + OFF_Q);
  f16* kbf = (f16*)((char*)d_ws + OFF_K);
  f16* vtb = (f16*)((char*)d_ws + OFF_VT);
  f16* opart = (f16*)((char*)d_ws + OFF_OP);
  float* ml = (float*)((char*)d_ws + OFF_ML);

  pack_w<<<dim3(72), dim3(256), 0, stream>>>(Wk, Wq, Wv, wpk);
  proj<<<dim3(NTOK / 16), dim3(256), 0, stream>>>(x, (const f16x8*)wpk, qb, kbf, vtb);
  if (ws_size >= (size_t)WS_NEED) {
    attn_part<<<dim3(288, NB), dim3(256), 0, stream>>>(qb, kbf, vtb, opart, ml);
    attn_combine<<<dim3(512), dim3(256), 0, stream>>>(opart, ml, out);
  } else {
    attn_mono<<<dim3(SEQ / 64, NB), dim3(256), 0, stream>>>(qb, kbf, vtb, out);
  }
}